// Round 23
// baseline (123.702 us; speedup 1.0000x reference)
//
#include <hip/hip_runtime.h>
#include <stdint.h>

#define D_ 128
#define H_ 8
#define B_ 4
#define L_ 2048
#define NH (B_*H_)

typedef __bf16 bf16x8 __attribute__((ext_vector_type(8)));
typedef float f32x4 __attribute__((ext_vector_type(4)));
typedef float f32x16 __attribute__((ext_vector_type(16)));
typedef unsigned short u16;
typedef u16 u16x2 __attribute__((ext_vector_type(2)));
typedef u16 u16x4 __attribute__((ext_vector_type(4)));
typedef u16 u16x8 __attribute__((ext_vector_type(8)));
typedef uint32_t u32x2 __attribute__((ext_vector_type(2)));
typedef uint32_t u32x4 __attribute__((ext_vector_type(4)));
typedef float fvec4 __attribute__((ext_vector_type(4)));

__device__ __forceinline__ u16 f2b(float f){
    uint32_t u = __builtin_bit_cast(uint32_t, f);
    u += 0x7fffu + ((u >> 16) & 1u);
    return (u16)(u >> 16);
}
__device__ __forceinline__ u16 f2b_native(float f){
    return __builtin_bit_cast(u16, (__bf16)f);
}
__device__ __forceinline__ uint32_t pk2(float a, float b){
    u16x2 v = { f2b_native(a), f2b_native(b) };
    return __builtin_bit_cast(uint32_t, v);
}
__device__ __forceinline__ float ex2(float x){
#if __has_builtin(__builtin_amdgcn_exp2f)
    return __builtin_amdgcn_exp2f(x);
#else
    return exp2f(x);
#endif
}
__device__ __forceinline__ u32x2 permswap(uint32_t a, uint32_t b){
#if __has_builtin(__builtin_amdgcn_permlane32_swap)
    return __builtin_amdgcn_permlane32_swap(a, b, false, false);
#else
    asm volatile("v_permlane32_swap_b32 %0, %1" : "+v"(a), "+v"(b));
    u32x2 r; r[0] = a; r[1] = b; return r;
#endif
}
__device__ __forceinline__ bf16x8 asbf(u16x8 v){ return __builtin_bit_cast(bf16x8, v); }
#define MFMA(a,b,c)   __builtin_amdgcn_mfma_f32_16x16x32_bf16((a),(b),(c),0,0,0)
#define MFMA32(a,b,c) __builtin_amdgcn_mfma_f32_32x32x16_bf16((a),(b),(c),0,0,0)

__device__ __forceinline__ void gld16(const u16* g, u16* l){
    __builtin_amdgcn_global_load_lds(
        (const __attribute__((address_space(1))) void*)g,
        (__attribute__((address_space(3))) void*)l, 16, 0, 0);
}

// ---------------- kernel 0: convert x -> bf16 AND W -> bf16 transposed tiles ----------------
__global__ __launch_bounds__(256)
void cvt_all(const float* __restrict__ x, const float* __restrict__ Wq,
             const float* __restrict__ Wk, const float* __restrict__ Wv,
             const float* __restrict__ Wu,
             u16* __restrict__ xb, u16* __restrict__ wT, u16* __restrict__ wuT)
{
    const int blk = blockIdx.x;
    const int t = threadIdx.x;
    if (blk < 512){
        size_t i = ((size_t)blk*256 + t)*8;
        fvec4 lo = *(const fvec4*)&x[i];
        fvec4 hi = *(const fvec4*)&x[i+4];
        u16x8 u;
        for (int j=0;j<4;++j){ u[j]=f2b(lo[j]); u[4+j]=f2b(hi[j]); }
        *(u16x8*)&xb[i] = u;
        return;
    }
    __shared__ __align__(16) u16 T[128][144];
    const int b = blk - 512;
    const float* src; int ld, coff, roff; u16* dst;
    if (b < 24){
        int mat = b>>3, head = b&7;
        src = (mat==0)?Wq:((mat==1)?Wk:Wv); ld = D_*H_; coff = head*128; roff = 0;
        dst = wT + (size_t)b*16384;
    } else {
        src = Wu; ld = D_; coff = 0; roff = (b-24)*128;
        dst = wuT + (size_t)(b-24)*16384;
    }
    for (int it=0; it<16; ++it){
        int k = it*8 + (t>>5), n0 = (t&31)*4;
        fvec4 wv = *(const fvec4*)&src[(size_t)(roff+k)*ld + coff + n0];
        for (int i=0;i<4;++i) T[n0+i][k] = f2b(wv[i]);
    }
    __syncthreads();
    for (int it=0; it<8; ++it){
        int gi = it*256 + t; int n = gi>>4, g = gi&15;
        *(u16x8*)&dst[n*128 + g*8] = *(const u16x8*)&T[n][(g^(n&7))*8];
    }
}

// ---------------- kernel 1: QKV projection — W staged once, X double-buffered ----------------
// grid (24 combos, 32 rt-groups) = 768 blocks (= 3 x 256 CUs, exact).
// Block owns (head,mat) + 2 row-tiles of 128: W tile staged ONCE (halves W
// traffic vs per-tile staging), X 2-ring; order: stage W+X0 -> fence ->
// issue X1 async -> compute(0) -> fence (X1 landed; vmcnt clean, no stores
// yet) -> stores(0) overlap compute(1) -> stores(1).
// K out layout (per bh, per 64-kv tile): [16 d-granules][64 rows][8] u16
// V out layout (per bh, per 64-kv tile): [8 kv-granules][128 d][8] u16
__global__ __launch_bounds__(256)
void qkv_proj(const u16* __restrict__ xb, const u16* __restrict__ wT,
              u16* __restrict__ q_ws, u16* __restrict__ k_ws, u16* __restrict__ v_ws)
{
    const int head = blockIdx.x & 7;
    const int mat  = blockIdx.x >> 3;
    const int rtg  = blockIdx.y;

    __shared__ __align__(16) u16 Xs[2][128*128];
    __shared__ __align__(16) u16 Ws[128*128];

    const int t = threadIdx.x;
    const u16* wsrc = wT + (size_t)(mat*8 + head)*16384;

    auto stageX = [&](int buf, int row0){
        #pragma unroll
        for (int it=0; it<8; ++it){
            int gi = it*256 + t;
            int r = gi>>4, g = gi&15;
            gld16(&xb[(size_t)(row0+r)*D_ + ((g ^ (r&7))*8)], &Xs[buf][(it*256 + (t>>6)*64)*8]);
        }
    };

    // stage W (once) + X tile 0
    for (int it=0; it<8; ++it)
        gld16(&wsrc[(it*256 + t)*8], &Ws[(it*256 + (t>>6)*64)*8]);
    stageX(0, (rtg*2)*128);
    asm volatile("s_waitcnt vmcnt(0)" ::: "memory");
    __builtin_amdgcn_s_barrier();

    stageX(1, (rtg*2+1)*128);   // async; lands during compute(0)

    const int wave = t>>6, lane = t&63;
    const int wr = wave>>1, wc = wave&1;
    const int lrow = lane&15, lgrp = lane>>4;
    const int swz = lrow&7;
    const float qscale = 0.12751879455370425f;  // log2(e)/sqrt(128)

    #pragma unroll
    for (int tt=0; tt<2; ++tt){
        const int row0 = (rtg*2+tt)*128;

        f32x4 acc[4][4] = {};
        #pragma unroll
        for (int kc=0;kc<4;++kc){
            const int gd = kc*4 + lgrp;
            bf16x8 a[4], bfr[4];
            #pragma unroll
            for (int mr=0;mr<4;++mr)
                a[mr] = asbf(*(const u16x8*)&Xs[tt][(wr*64+mr*16+lrow)*128 + ((gd ^ swz)*8)]);
            #pragma unroll
            for (int nr=0;nr<4;++nr)
                bfr[nr] = asbf(*(const u16x8*)&Ws[(wc*64+nr*16+lrow)*128 + ((gd ^ swz)*8)]);
            #pragma unroll
            for (int mr=0;mr<4;++mr)
                #pragma unroll
                for (int nr=0;nr<4;++nr)
                    acc[mr][nr] = MFMA(a[mr], bfr[nr], acc[mr][nr]);
        }

        if (tt == 0){
            // X1 landed; no stores issued yet so vmcnt(0) only waits the DMAs
            asm volatile("s_waitcnt vmcnt(0)" ::: "memory");
            __builtin_amdgcn_s_barrier();
        }

        for (int mr=0;mr<4;++mr){
            for (int nr=0;nr<4;++nr){
                f32x4 v = acc[mr][nr];
                int baserow = row0 + wr*64 + mr*16 + lgrp*4;
                int cd = wc*64 + nr*16 + lrow;
                int b  = baserow / L_;
                int l  = baserow % L_;
                int bh = b*H_ + head;
                if (mat==2){
                    u16x4 pv;
                    for (int r=0;r<4;++r) pv[r] = f2b(v[r]);
                    size_t va = (size_t)bh*D_*L_ + (size_t)(l>>6)*8192 + ((l&63)>>3)*1024 + cd*8 + (l&7);
                    *(u16x4*)&v_ws[va] = pv;
                } else if (mat==1){
                    for (int r=0;r<4;++r){
                        int l2 = l + r;
                        size_t ka = (size_t)bh*L_*D_ + (size_t)(l2>>6)*8192 + (cd>>3)*512 + (l2&63)*8 + (cd&7);
                        k_ws[ka] = f2b(v[r]);
                    }
                } else {
                    for (int r=0;r<4;++r)
                        q_ws[((size_t)bh*L_ + (l + r))*D_ + cd] = f2b(v[r]*qscale);
                }
            }
        }
    }
}

// ---------------- kernel 2: flash attention (R17 known-good: 76.5 us) ----------------
// 256 blocks (1/CU) x 512 threads (8 waves); wave owns 32 q rows; q-tile 256.
// 4-deep ring; iteration j: stage tiles 2j+2,2j+3, compute tiles 2j,2j+1,
// ONE vmcnt(0)+barrier per PAIR (16 fences). Granule-major K/V layout:
// DMA fully linear, ds_read_b128 bank-uniform (conflicts = 0).
// Swapped QK^T (mfma(K,Q)), 4-way ILP accumulators, lane-local softmax,
// P via pk2+permlane32_swap, no P LDS round-trip.
__global__ __launch_bounds__(512)
void attn(const u16* __restrict__ q_ws, const u16* __restrict__ k_ws,
          const u16* __restrict__ v_ws, u16* __restrict__ o_ws)
{
    const int wg = ((blockIdx.x & 7) << 5) | (blockIdx.x >> 3);
    const int qt = wg & 7;
    const int bh = wg >> 3;

    const int t = threadIdx.x, wave = t>>6, lane = t&63;
    const int q31 = lane & 31;
    const int hi  = lane >> 5;

    __shared__ __align__(16) u16 Kb[4][64*128];
    __shared__ __align__(16) u16 Vb[4][128*64];

    const int q0 = qt*256 + wave*32;

    bf16x8 qf[8];
    #pragma unroll
    for (int ks=0; ks<8; ++ks)
        qf[ks] = asbf(*(const u16x8*)&q_ws[((size_t)bh*L_ + q0 + q31)*D_ + ks*16 + hi*8]);

    const u16* kp = k_ws + (size_t)bh*L_*D_;
    const u16* vp = v_ws + (size_t)bh*D_*L_;

    auto stage = [&](int buf){   // 4 gld16 per thread; fully linear
        #pragma unroll
        for (int i=0;i<2;++i){
            gld16(kp + (i*512 + t)*8, &Kb[buf][(i*512 + wave*64)*8]);
            gld16(vp + (i*512 + t)*8, &Vb[buf][(i*512 + wave*64)*8]);
        }
        kp += 8192;
        vp += 8192;
    };

    auto qkt = [&](int buf, f32x16& S0, f32x16& S1){
        f32x16 s0a = {}, s0b = {}, s1a = {}, s1b = {};
        #pragma unroll
        for (int ks=0; ks<4; ++ks){
            const int g0 = ks*2+hi, g1 = (ks+4)*2+hi;
            bf16x8 ka0 = asbf(*(const u16x8*)&Kb[buf][g0*512 + q31*8]);
            bf16x8 ka1 = asbf(*(const u16x8*)&Kb[buf][g1*512 + q31*8]);
            bf16x8 kb0 = asbf(*(const u16x8*)&Kb[buf][g0*512 + (32+q31)*8]);
            bf16x8 kb1 = asbf(*(const u16x8*)&Kb[buf][g1*512 + (32+q31)*8]);
            s0a = MFMA32(ka0, qf[ks],   s0a);
            s0b = MFMA32(ka1, qf[ks+4], s0b);
            s1a = MFMA32(kb0, qf[ks],   s1a);
            s1b = MFMA32(kb1, qf[ks+4], s1b);
        }
        S0 = s0a + s0b;
        S1 = s1a + s1b;
    };

    float lsA = 0.f, lsB = 0.f;
    f32x16 o4[4] = {};

    stage(0);
    stage(1);
    asm volatile("s_waitcnt vmcnt(0)" ::: "memory");
    __builtin_amdgcn_s_barrier();

    #define SM_PV(SREG, KS, BUF) do { \
        float p0 = ex2(SREG[((KS&1)*8)+0]); \
        float p1 = ex2(SREG[((KS&1)*8)+1]); \
        float p2 = ex2(SREG[((KS&1)*8)+2]); \
        float p3 = ex2(SREG[((KS&1)*8)+3]); \
        float p4 = ex2(SREG[((KS&1)*8)+4]); \
        float p5 = ex2(SREG[((KS&1)*8)+5]); \
        float p6 = ex2(SREG[((KS&1)*8)+6]); \
        float p7 = ex2(SREG[((KS&1)*8)+7]); \
        lsA += (p0+p1)+(p2+p3); \
        lsB += (p4+p5)+(p6+p7); \
        uint32_t cA = pk2(p0,p1), cB = pk2(p2,p3); \
        uint32_t cC = pk2(p4,p5), cD = pk2(p6,p7); \
        u32x2 r0 = permswap(cA, cC); \
        u32x2 r1 = permswap(cB, cD); \
        u32x4 wv; \
        wv[0] = r0[0];  wv[1] = r1[0]; \
        wv[2] = r0[1];  wv[3] = r1[1]; \
        bf16x8 pa = __builtin_bit_cast(bf16x8, wv); \
        __builtin_amdgcn_s_setprio(1); \
        _Pragma("unroll") \
        for (int nc2=0; nc2<4; ++nc2){ \
            bf16x8 vb = asbf(*(const u16x8*)&Vb[BUF][ (KS*2+hi)*1024 + (nc2*32+q31)*8 ]); \
            o4[nc2] = MFMA32(pa, vb, o4[nc2]); \
        } \
        __builtin_amdgcn_s_setprio(0); \
    } while(0)

    const int NJ = L_/128;   // 16 pair-iterations
    for (int j=0; j<NJ; ++j){
        const int sa = (2*j) & 3, sb = (2*j+1) & 3;
        if (j < NJ-1){
            stage((2*j+2) & 3);
            stage((2*j+3) & 3);
        }

        f32x16 sA0, sA1;
        __builtin_amdgcn_s_setprio(1);
        qkt(sa, sA0, sA1);
        __builtin_amdgcn_s_setprio(0);
        SM_PV(sA0, 0, sa);
        SM_PV(sA0, 1, sa);
        SM_PV(sA1, 2, sa);
        SM_PV(sA1, 3, sa);

        f32x16 sB0, sB1;
        __builtin_amdgcn_s_setprio(1);
        qkt(sb, sB0, sB1);
        __builtin_amdgcn_s_setprio(0);
        SM_PV(sB0, 0, sb);
        SM_PV(sB0, 1, sb);
        SM_PV(sB1, 2, sb);
        SM_PV(sB1, 3, sb);

        if (j < NJ-1){
            asm volatile("s_waitcnt vmcnt(0)" ::: "memory");
            __builtin_amdgcn_s_barrier();
        }
    }
    #undef SM_PV

    float lsum = lsA + lsB;
    lsum += __shfl_xor(lsum, 32, 64);
    float inv = 1.0f / lsum;

    const int b = bh / H_, h = bh % H_;
    #pragma unroll
    for (int m=0; m<4; ++m){
        #pragma unroll
        for (int i=0; i<4; ++i){
            const int reg = m*4 + i;
            const int row = i + 8*m + 4*hi;
            float riv = __shfl(inv, row, 64);
            const int l = q0 + row;
            size_t base = ((size_t)(b*L_ + l))*(D_*H_) + h*128 + q31;
            #pragma unroll
            for (int nc2=0; nc2<4; ++nc2)
                o_ws[base + nc2*32] = f2b_native(o4[nc2][reg] * riv);
        }
    }
}

// ---------------- kernel 3: output projection + bias (double-buffered staging) ----------------
__global__ __launch_bounds__(256)
void out_proj(const u16* __restrict__ o_ws, const u16* __restrict__ wuT,
              const float* __restrict__ bu, float* __restrict__ out)
{
    const int rt = blockIdx.x;
    const int t = threadIdx.x, wave = t>>6, lane = t&63;
    const int wr = wave>>1, wc = wave&1;
    const int lrow = lane&15, lgrp = lane>>4;
    const int swz = lrow&7;

    __shared__ __align__(16) u16 As[2][32*128];
    __shared__ __align__(16) u16 Ws[2][128*128];

    const int row0 = rt*32;
    f32x4 acc[4] = {};

    auto stage = [&](int ks){
        const int buf = ks & 1;
        int gi = t;
        int r = gi>>4, g = gi&15;
        gld16(&o_ws[(size_t)(row0+r)*(D_*H_) + ks*128 + ((g ^ (r&7))*8)], &As[buf][((t>>6)*64)*8]);
        gi = 256 + t;
        r = gi>>4; g = gi&15;
        gld16(&o_ws[(size_t)(row0+r)*(D_*H_) + ks*128 + ((g ^ (r&7))*8)], &As[buf][(256 + (t>>6)*64)*8]);
        const u16* wsrc = wuT + (size_t)ks*16384;
        #pragma unroll
        for (int it=0; it<8; ++it)
            gld16(&wsrc[(it*256 + t)*8], &Ws[buf][(it*256 + (t>>6)*64)*8]);
    };

    stage(0);
    for (int ks=0; ks<8; ++ks){
        const int buf = ks & 1;
        if (ks < 7){
            stage(ks+1);
            asm volatile("s_waitcnt vmcnt(10)" ::: "memory");
        } else {
            asm volatile("s_waitcnt vmcnt(0)" ::: "memory");
        }
        __builtin_amdgcn_s_barrier();

        #pragma unroll
        for (int kc=0;kc<4;++kc){
            const int gd = kc*4 + lgrp;
            bf16x8 a = asbf(*(const u16x8*)&As[buf][(wr*16+lrow)*128 + ((gd ^ swz)*8)]);
            #pragma unroll
            for (int nc=0;nc<4;++nc){
                bf16x8 b = asbf(*(const u16x8*)&Ws[buf][(wc*64+nc*16+lrow)*128 + ((gd ^ swz)*8)]);
                acc[nc] = MFMA(a, b, acc[nc]);
            }
        }
        __builtin_amdgcn_s_barrier();
    }

    for (int nc=0;nc<4;++nc){
        for (int r=0;r<4;++r){
            int row = row0 + wr*16 + lgrp*4 + r;
            int n = wc*64 + nc*16 + lrow;
            out[(size_t)row*D_ + n] = acc[nc][r] + bu[n];
        }
    }
}

// ---------------- launcher ----------------
extern "C" void kernel_launch(void* const* d_in, const int* in_sizes, int n_in,
                              void* d_out, int out_size, void* d_ws, size_t ws_size,
                              hipStream_t stream)
{
    const float* x  = (const float*)d_in[0];
    const float* Wq = (const float*)d_in[1];
    const float* Wk = (const float*)d_in[2];
    const float* Wv = (const float*)d_in[3];
    const float* Wu = (const float*)d_in[4];
    const float* bu = (const float*)d_in[5];
    float* out = (float*)d_out;

    u16* ws = (u16*)d_ws;
    const size_t SZ = (size_t)NH * L_ * D_;   // 8,388,608
    u16* q_ws = ws;
    u16* k_ws = q_ws + SZ;
    u16* v_ws = k_ws + SZ;
    u16* o_ws = v_ws + SZ;
    u16* x_bf = o_ws + SZ;                    // 1,048,576
    u16* wT   = x_bf + (size_t)B_*L_*D_;      // 24*16384
    u16* wuT  = wT + 24*16384;                // 8*16384

    cvt_all<<<dim3(544), 256, 0, stream>>>(x, Wq, Wk, Wv, Wu, x_bf, wT, wuT);
    qkv_proj<<<dim3(24, 32), 256, 0, stream>>>(x_bf, wT, q_ws, k_ws, v_ws);
    attn<<<dim3((L_/256)*NH), 512, 0, stream>>>(q_ws, k_ws, v_ws, o_ws);
    out_proj<<<dim3((B_*L_)/32), 256, 0, stream>>>(o_ws, wuT, bu, out);
}

// Round 24
// 118.993 us; speedup vs baseline: 1.0396x; 1.0396x over previous
//
#include <hip/hip_runtime.h>
#include <stdint.h>

#define D_ 128
#define H_ 8
#define B_ 4
#define L_ 2048
#define NH (B_*H_)

typedef __bf16 bf16x8 __attribute__((ext_vector_type(8)));
typedef float f32x4 __attribute__((ext_vector_type(4)));
typedef float f32x16 __attribute__((ext_vector_type(16)));
typedef unsigned short u16;
typedef u16 u16x2 __attribute__((ext_vector_type(2)));
typedef u16 u16x4 __attribute__((ext_vector_type(4)));
typedef u16 u16x8 __attribute__((ext_vector_type(8)));
typedef uint32_t u32x2 __attribute__((ext_vector_type(2)));
typedef uint32_t u32x4 __attribute__((ext_vector_type(4)));
typedef float fvec4 __attribute__((ext_vector_type(4)));

__device__ __forceinline__ u16 f2b(float f){
    uint32_t u = __builtin_bit_cast(uint32_t, f);
    u += 0x7fffu + ((u >> 16) & 1u);
    return (u16)(u >> 16);
}
__device__ __forceinline__ u16 f2b_native(float f){
    return __builtin_bit_cast(u16, (__bf16)f);
}
__device__ __forceinline__ uint32_t pk2(float a, float b){
    u16x2 v = { f2b_native(a), f2b_native(b) };
    return __builtin_bit_cast(uint32_t, v);
}
__device__ __forceinline__ float ex2(float x){
#if __has_builtin(__builtin_amdgcn_exp2f)
    return __builtin_amdgcn_exp2f(x);
#else
    return exp2f(x);
#endif
}
__device__ __forceinline__ u32x2 permswap(uint32_t a, uint32_t b){
#if __has_builtin(__builtin_amdgcn_permlane32_swap)
    return __builtin_amdgcn_permlane32_swap(a, b, false, false);
#else
    asm volatile("v_permlane32_swap_b32 %0, %1" : "+v"(a), "+v"(b));
    u32x2 r; r[0] = a; r[1] = b; return r;
#endif
}
__device__ __forceinline__ bf16x8 asbf(u16x8 v){ return __builtin_bit_cast(bf16x8, v); }
#define MFMA(a,b,c)   __builtin_amdgcn_mfma_f32_16x16x32_bf16((a),(b),(c),0,0,0)
#define MFMA32(a,b,c) __builtin_amdgcn_mfma_f32_32x32x16_bf16((a),(b),(c),0,0,0)

__device__ __forceinline__ void gld16(const u16* g, u16* l){
    __builtin_amdgcn_global_load_lds(
        (const __attribute__((address_space(1))) void*)g,
        (__attribute__((address_space(3))) void*)l, 16, 0, 0);
}

// ---------------- kernel 0: convert x -> bf16 AND W -> bf16 transposed tiles ----------------
__global__ __launch_bounds__(256)
void cvt_all(const float* __restrict__ x, const float* __restrict__ Wq,
             const float* __restrict__ Wk, const float* __restrict__ Wv,
             const float* __restrict__ Wu,
             u16* __restrict__ xb, u16* __restrict__ wT, u16* __restrict__ wuT)
{
    const int blk = blockIdx.x;
    const int t = threadIdx.x;
    if (blk < 512){
        size_t i = ((size_t)blk*256 + t)*8;
        fvec4 lo = *(const fvec4*)&x[i];
        fvec4 hi = *(const fvec4*)&x[i+4];
        u16x8 u;
        for (int j=0;j<4;++j){ u[j]=f2b(lo[j]); u[4+j]=f2b(hi[j]); }
        *(u16x8*)&xb[i] = u;
        return;
    }
    __shared__ __align__(16) u16 T[128][144];
    const int b = blk - 512;
    const float* src; int ld, coff, roff; u16* dst;
    if (b < 24){
        int mat = b>>3, head = b&7;
        src = (mat==0)?Wq:((mat==1)?Wk:Wv); ld = D_*H_; coff = head*128; roff = 0;
        dst = wT + (size_t)b*16384;
    } else {
        src = Wu; ld = D_; coff = 0; roff = (b-24)*128;
        dst = wuT + (size_t)(b-24)*16384;
    }
    for (int it=0; it<16; ++it){
        int k = it*8 + (t>>5), n0 = (t&31)*4;
        fvec4 wv = *(const fvec4*)&src[(size_t)(roff+k)*ld + coff + n0];
        for (int i=0;i<4;++i) T[n0+i][k] = f2b(wv[i]);
    }
    __syncthreads();
    for (int it=0; it<8; ++it){
        int gi = it*256 + t; int n = gi>>4, g = gi&15;
        *(u16x8*)&dst[n*128 + g*8] = *(const u16x8*)&T[n][(g^(n&7))*8];
    }
}

// ---------------- kernel 1: QKV projection (DMA-staged both operands) ----------------
// K layout (per bh, per 64-kv tile): [16 d-granules][64 rows][8] u16
// V layout (per bh, per 64-kv tile): [8 kv-granules][128 d][8] u16
__global__ __launch_bounds__(256)
void qkv_proj(const u16* __restrict__ xb, const u16* __restrict__ wT,
              u16* __restrict__ q_ws, u16* __restrict__ k_ws, u16* __restrict__ v_ws)
{
    const int head = blockIdx.x;
    const int rt   = blockIdx.y;
    const int mat  = blockIdx.z;

    __shared__ __align__(16) u16 Xs[128*128];
    __shared__ __align__(16) u16 Ws[128*128];

    const int t = threadIdx.x;
    const int row0 = rt*128;
    const u16* wsrc = wT + (size_t)(mat*8 + head)*16384;

    for (int it=0; it<8; ++it){
        int gi = it*256 + t;
        int r = gi>>4, g = gi&15;
        gld16(&xb[(size_t)(row0+r)*D_ + ((g ^ (r&7))*8)], &Xs[(it*256 + (t>>6)*64)*8]);
        gld16(&wsrc[gi*8],                                &Ws[(it*256 + (t>>6)*64)*8]);
    }
    asm volatile("s_waitcnt vmcnt(0)" ::: "memory");
    __builtin_amdgcn_s_barrier();

    const int wave = t>>6, lane = t&63;
    const int wr = wave>>1, wc = wave&1;
    const int lrow = lane&15, lgrp = lane>>4;
    const int swz = lrow&7;

    f32x4 acc[4][4] = {};
    #pragma unroll
    for (int kc=0;kc<4;++kc){
        const int gd = kc*4 + lgrp;
        bf16x8 a[4], bfr[4];
        #pragma unroll
        for (int mr=0;mr<4;++mr)
            a[mr] = asbf(*(const u16x8*)&Xs[(wr*64+mr*16+lrow)*128 + ((gd ^ swz)*8)]);
        #pragma unroll
        for (int nr=0;nr<4;++nr)
            bfr[nr] = asbf(*(const u16x8*)&Ws[(wc*64+nr*16+lrow)*128 + ((gd ^ swz)*8)]);
        #pragma unroll
        for (int mr=0;mr<4;++mr)
            #pragma unroll
            for (int nr=0;nr<4;++nr)
                acc[mr][nr] = MFMA(a[mr], bfr[nr], acc[mr][nr]);
    }

    const float qscale = 0.12751879455370425f;  // log2(e)/sqrt(128)
    for (int mr=0;mr<4;++mr){
        for (int nr=0;nr<4;++nr){
            f32x4 v = acc[mr][nr];
            int baserow = row0 + wr*64 + mr*16 + lgrp*4;
            int cd = wc*64 + nr*16 + lrow;
            int b  = baserow / L_;
            int l  = baserow % L_;
            int bh = b*H_ + head;
            if (mat==2){
                u16x4 pv;
                for (int r=0;r<4;++r) pv[r] = f2b(v[r]);
                size_t va = (size_t)bh*D_*L_ + (size_t)(l>>6)*8192 + ((l&63)>>3)*1024 + cd*8 + (l&7);
                *(u16x4*)&v_ws[va] = pv;
            } else if (mat==1){
                for (int r=0;r<4;++r){
                    int l2 = l + r;
                    size_t ka = (size_t)bh*L_*D_ + (size_t)(l2>>6)*8192 + (cd>>3)*512 + (l2&63)*8 + (cd&7);
                    k_ws[ka] = f2b(v[r]);
                }
            } else {
                for (int r=0;r<4;++r)
                    q_ws[((size_t)bh*L_ + (l + r))*D_ + cd] = f2b(v[r]*qscale);
            }
        }
    }
}

// ---------------- kernel 2: flash attention (R17 known-good: 76.5 us) ----------------
// 256 blocks (1/CU) x 512 threads (8 waves); wave owns 32 q rows; q-tile 256.
// 4-deep ring; iteration j: stage tiles 2j+2,2j+3, compute tiles 2j,2j+1,
// ONE vmcnt(0)+barrier per PAIR (16 fences). Granule-major K/V layout:
// DMA fully linear, ds_read_b128 bank-uniform (conflicts = 0).
// Swapped QK^T (mfma(K,Q)), 4-way ILP accumulators, lane-local softmax,
// P via pk2+permlane32_swap, no P LDS round-trip.
__global__ __launch_bounds__(512)
void attn(const u16* __restrict__ q_ws, const u16* __restrict__ k_ws,
          const u16* __restrict__ v_ws, u16* __restrict__ o_ws)
{
    const int wg = ((blockIdx.x & 7) << 5) | (blockIdx.x >> 3);
    const int qt = wg & 7;
    const int bh = wg >> 3;

    const int t = threadIdx.x, wave = t>>6, lane = t&63;
    const int q31 = lane & 31;
    const int hi  = lane >> 5;

    __shared__ __align__(16) u16 Kb[4][64*128];
    __shared__ __align__(16) u16 Vb[4][128*64];

    const int q0 = qt*256 + wave*32;

    bf16x8 qf[8];
    #pragma unroll
    for (int ks=0; ks<8; ++ks)
        qf[ks] = asbf(*(const u16x8*)&q_ws[((size_t)bh*L_ + q0 + q31)*D_ + ks*16 + hi*8]);

    const u16* kp = k_ws + (size_t)bh*L_*D_;
    const u16* vp = v_ws + (size_t)bh*D_*L_;

    auto stage = [&](int buf){   // 4 gld16 per thread; fully linear
        #pragma unroll
        for (int i=0;i<2;++i){
            gld16(kp + (i*512 + t)*8, &Kb[buf][(i*512 + wave*64)*8]);
            gld16(vp + (i*512 + t)*8, &Vb[buf][(i*512 + wave*64)*8]);
        }
        kp += 8192;
        vp += 8192;
    };

    auto qkt = [&](int buf, f32x16& S0, f32x16& S1){
        f32x16 s0a = {}, s0b = {}, s1a = {}, s1b = {};
        #pragma unroll
        for (int ks=0; ks<4; ++ks){
            const int g0 = ks*2+hi, g1 = (ks+4)*2+hi;
            bf16x8 ka0 = asbf(*(const u16x8*)&Kb[buf][g0*512 + q31*8]);
            bf16x8 ka1 = asbf(*(const u16x8*)&Kb[buf][g1*512 + q31*8]);
            bf16x8 kb0 = asbf(*(const u16x8*)&Kb[buf][g0*512 + (32+q31)*8]);
            bf16x8 kb1 = asbf(*(const u16x8*)&Kb[buf][g1*512 + (32+q31)*8]);
            s0a = MFMA32(ka0, qf[ks],   s0a);
            s0b = MFMA32(ka1, qf[ks+4], s0b);
            s1a = MFMA32(kb0, qf[ks],   s1a);
            s1b = MFMA32(kb1, qf[ks+4], s1b);
        }
        S0 = s0a + s0b;
        S1 = s1a + s1b;
    };

    float lsA = 0.f, lsB = 0.f;
    f32x16 o4[4] = {};

    stage(0);
    stage(1);
    asm volatile("s_waitcnt vmcnt(0)" ::: "memory");
    __builtin_amdgcn_s_barrier();

    #define SM_PV(SREG, KS, BUF) do { \
        float p0 = ex2(SREG[((KS&1)*8)+0]); \
        float p1 = ex2(SREG[((KS&1)*8)+1]); \
        float p2 = ex2(SREG[((KS&1)*8)+2]); \
        float p3 = ex2(SREG[((KS&1)*8)+3]); \
        float p4 = ex2(SREG[((KS&1)*8)+4]); \
        float p5 = ex2(SREG[((KS&1)*8)+5]); \
        float p6 = ex2(SREG[((KS&1)*8)+6]); \
        float p7 = ex2(SREG[((KS&1)*8)+7]); \
        lsA += (p0+p1)+(p2+p3); \
        lsB += (p4+p5)+(p6+p7); \
        uint32_t cA = pk2(p0,p1), cB = pk2(p2,p3); \
        uint32_t cC = pk2(p4,p5), cD = pk2(p6,p7); \
        u32x2 r0 = permswap(cA, cC); \
        u32x2 r1 = permswap(cB, cD); \
        u32x4 wv; \
        wv[0] = r0[0];  wv[1] = r1[0]; \
        wv[2] = r0[1];  wv[3] = r1[1]; \
        bf16x8 pa = __builtin_bit_cast(bf16x8, wv); \
        __builtin_amdgcn_s_setprio(1); \
        _Pragma("unroll") \
        for (int nc2=0; nc2<4; ++nc2){ \
            bf16x8 vb = asbf(*(const u16x8*)&Vb[BUF][ (KS*2+hi)*1024 + (nc2*32+q31)*8 ]); \
            o4[nc2] = MFMA32(pa, vb, o4[nc2]); \
        } \
        __builtin_amdgcn_s_setprio(0); \
    } while(0)

    const int NJ = L_/128;   // 16 pair-iterations
    for (int j=0; j<NJ; ++j){
        const int sa = (2*j) & 3, sb = (2*j+1) & 3;
        if (j < NJ-1){
            stage((2*j+2) & 3);
            stage((2*j+3) & 3);
        }

        f32x16 sA0, sA1;
        __builtin_amdgcn_s_setprio(1);
        qkt(sa, sA0, sA1);
        __builtin_amdgcn_s_setprio(0);
        SM_PV(sA0, 0, sa);
        SM_PV(sA0, 1, sa);
        SM_PV(sA1, 2, sa);
        SM_PV(sA1, 3, sa);

        f32x16 sB0, sB1;
        __builtin_amdgcn_s_setprio(1);
        qkt(sb, sB0, sB1);
        __builtin_amdgcn_s_setprio(0);
        SM_PV(sB0, 0, sb);
        SM_PV(sB0, 1, sb);
        SM_PV(sB1, 2, sb);
        SM_PV(sB1, 3, sb);

        if (j < NJ-1){
            asm volatile("s_waitcnt vmcnt(0)" ::: "memory");
            __builtin_amdgcn_s_barrier();
        }
    }
    #undef SM_PV

    float lsum = lsA + lsB;
    lsum += __shfl_xor(lsum, 32, 64);
    float inv = 1.0f / lsum;

    const int b = bh / H_, h = bh % H_;
    #pragma unroll
    for (int m=0; m<4; ++m){
        #pragma unroll
        for (int i=0; i<4; ++i){
            const int reg = m*4 + i;
            const int row = i + 8*m + 4*hi;
            float riv = __shfl(inv, row, 64);
            const int l = q0 + row;
            size_t base = ((size_t)(b*L_ + l))*(D_*H_) + h*128 + q31;
            #pragma unroll
            for (int nc2=0; nc2<4; ++nc2)
                o_ws[base + nc2*32] = f2b_native(o4[nc2][reg] * riv);
        }
    }
}

// ---------------- kernel 3: output projection + bias (double-buffered staging) ----------------
__global__ __launch_bounds__(256)
void out_proj(const u16* __restrict__ o_ws, const u16* __restrict__ wuT,
              const float* __restrict__ bu, float* __restrict__ out)
{
    const int rt = blockIdx.x;
    const int t = threadIdx.x, wave = t>>6, lane = t&63;
    const int wr = wave>>1, wc = wave&1;
    const int lrow = lane&15, lgrp = lane>>4;
    const int swz = lrow&7;

    __shared__ __align__(16) u16 As[2][32*128];
    __shared__ __align__(16) u16 Ws[2][128*128];

    const int row0 = rt*32;
    f32x4 acc[4] = {};

    auto stage = [&](int ks){
        const int buf = ks & 1;
        int gi = t;
        int r = gi>>4, g = gi&15;
        gld16(&o_ws[(size_t)(row0+r)*(D_*H_) + ks*128 + ((g ^ (r&7))*8)], &As[buf][((t>>6)*64)*8]);
        gi = 256 + t;
        r = gi>>4; g = gi&15;
        gld16(&o_ws[(size_t)(row0+r)*(D_*H_) + ks*128 + ((g ^ (r&7))*8)], &As[buf][(256 + (t>>6)*64)*8]);
        const u16* wsrc = wuT + (size_t)ks*16384;
        #pragma unroll
        for (int it=0; it<8; ++it)
            gld16(&wsrc[(it*256 + t)*8], &Ws[buf][(it*256 + (t>>6)*64)*8]);
    };

    stage(0);
    for (int ks=0; ks<8; ++ks){
        const int buf = ks & 1;
        if (ks < 7){
            stage(ks+1);
            asm volatile("s_waitcnt vmcnt(10)" ::: "memory");
        } else {
            asm volatile("s_waitcnt vmcnt(0)" ::: "memory");
        }
        __builtin_amdgcn_s_barrier();

        #pragma unroll
        for (int kc=0;kc<4;++kc){
            const int gd = kc*4 + lgrp;
            bf16x8 a = asbf(*(const u16x8*)&As[buf][(wr*16+lrow)*128 + ((gd ^ swz)*8)]);
            #pragma unroll
            for (int nc=0;nc<4;++nc){
                bf16x8 b = asbf(*(const u16x8*)&Ws[buf][(wc*64+nc*16+lrow)*128 + ((gd ^ swz)*8)]);
                acc[nc] = MFMA(a, b, acc[nc]);
            }
        }
        __builtin_amdgcn_s_barrier();
    }

    for (int nc=0;nc<4;++nc){
        for (int r=0;r<4;++r){
            int row = row0 + wr*16 + lgrp*4 + r;
            int n = wc*64 + nc*16 + lrow;
            out[(size_t)row*D_ + n] = acc[nc][r] + bu[n];
        }
    }
}

// ---------------- launcher ----------------
extern "C" void kernel_launch(void* const* d_in, const int* in_sizes, int n_in,
                              void* d_out, int out_size, void* d_ws, size_t ws_size,
                              hipStream_t stream)
{
    const float* x  = (const float*)d_in[0];
    const float* Wq = (const float*)d_in[1];
    const float* Wk = (const float*)d_in[2];
    const float* Wv = (const float*)d_in[3];
    const float* Wu = (const float*)d_in[4];
    const float* bu = (const float*)d_in[5];
    float* out = (float*)d_out;

    u16* ws = (u16*)d_ws;
    const size_t SZ = (size_t)NH * L_ * D_;   // 8,388,608
    u16* q_ws = ws;
    u16* k_ws = q_ws + SZ;
    u16* v_ws = k_ws + SZ;
    u16* o_ws = v_ws + SZ;
    u16* x_bf = o_ws + SZ;                    // 1,048,576
    u16* wT   = x_bf + (size_t)B_*L_*D_;      // 24*16384
    u16* wuT  = wT + 24*16384;                // 8*16384

    cvt_all<<<dim3(544), 256, 0, stream>>>(x, Wq, Wk, Wv, Wu, x_bf, wT, wuT);
    qkv_proj<<<dim3(H_, (B_*L_)/128, 3), 256, 0, stream>>>(x_bf, wT, q_ws, k_ws, v_ws);
    attn<<<dim3((L_/256)*NH), 512, 0, stream>>>(q_ws, k_ws, v_ws, o_ws);
    out_proj<<<dim3((B_*L_)/32), 256, 0, stream>>>(o_ws, wuT, bu, out);
}